// Round 1
// 263.080 us; speedup vs baseline: 1.1221x; 1.1221x over previous
//
#include <hip/hip_runtime.h>
#include <math.h>

#define BB 512
#define TT 1024
#define KK 48
#define PF 6     // emission prefetch depth (register ring)
#define ISC 12   // state kept at 2^-12 scale for f16 range

typedef _Float16 half2v __attribute__((ext_vector_type(2)));

static constexpr float L2E = 1.4426950408889634f;   // log2(e)
static constexpr float LN2 = 0.6931471805599453f;   // ln(2)

__device__ __forceinline__ float wave_reduce_sum_f(float v) {
    #pragma unroll
    for (int m = 32; m >= 1; m >>= 1) v += __shfl_xor(v, m, 64);
    return v;
}
__device__ __forceinline__ int wave_reduce_sum_i(int v) {
    #pragma unroll
    for (int m = 32; m >= 1; m >>= 1) v += __shfl_xor(v, m, 64);
    return v;
}
__device__ __forceinline__ float rlane(float v, int i) {
    return __uint_as_float(__builtin_amdgcn_readlane(__float_as_uint(v), i));
}

// f16x2 dot product with f32 accumulate: v_dot2_f32_f16 (2 MACs / instr)
__device__ __forceinline__ float dot2(unsigned a, unsigned b, float c) {
#if __has_builtin(__builtin_amdgcn_fdot2)
    union { unsigned u; half2v h; } ua, ub;
    ua.u = a; ub.u = b;
    return __builtin_amdgcn_fdot2(ua.h, ub.h, c, false);
#else
    union { unsigned u; half2v h; } ua, ub;
    ua.u = a; ub.u = b;
    return c + (float)ua.h.x * (float)ub.h.x + (float)ua.h.y * (float)ub.h.y;
#endif
}

// Pack (u[j], u[j+1]) as f16x2 in-register: cvt -> DPP quad_perm swap -> byte-perm.
// Even lane j ends with (lo = u[j], hi = u[j+1]); readlanes target even lanes.
__device__ __forceinline__ unsigned pack_pair(float u) {
    union { _Float16 h; unsigned short s; } cv;
    cv.h = (_Float16)u;
    const unsigned own = cv.s;
    const unsigned nbr = (unsigned)__builtin_amdgcn_update_dpp(
        (int)own, (int)own, 0xB1 /*quad_perm [1,0,3,2]*/, 0xF, 0xF, false);
    return __builtin_amdgcn_perm(nbr, own, 0x05040100);
}

__device__ __forceinline__ int count_L(const void* mask, int b, int lane, unsigned w0) {
    int c = 0;
    if (w0 == 1u) {
        const int* mp = (const int*)mask + (size_t)b * TT;
        for (int t = lane; t < TT; t += 64) c += (mp[t] != 0);
    } else if (w0 == 0x3f800000u) {
        const float* mp = (const float*)mask + (size_t)b * TT;
        for (int t = lane; t < TT; t += 64) c += (mp[t] != 0.0f);
    } else {
        const unsigned char* mp = (const unsigned char*)mask + (size_t)b * TT;
        for (int t = lane; t < TT; t += 64) c += (mp[t] != 0);
    }
    return wave_reduce_sum_i(c);
}

// Scaled linear-space scan over nsteps emission steps.
// FWD=0: alpha_t = (M alpha_{t-1}) .* E_t, emission t = t0 + s (t0 = 1).
// BWD=1: beta_{t-1} = M^T (E_t .* beta_t), emission t = t0 - s (t0 = L-1).
// State u is f32 per lane; renorm is an EXACT power-of-2 (exponent bits + ldexp),
// with the normalizer 1 step delayed (off the critical chain). The accumulated
// exponent is an exact integer; D_out = Dbase + iD with true log2(vec) = log2(u)+D.
template <int BWD>
__device__ __forceinline__ void scan_half(
    const float* __restrict__ em, const float* __restrict__ transitions,
    const float* __restrict__ boundary, int nsteps, int t0, int lane,
    float& u_out, float& D_out)
{
    const int jj = (lane < KK) ? lane : 0;
    unsigned Mp[KK / 2];   // fwd: row jj of exp(T); bwd: column jj of exp(T)
    #pragma unroll
    for (int i = 0; i < KK / 2; ++i) {
        float m0, m1;
        if (BWD) { m0 = transitions[(2*i)   * KK + jj];
                   m1 = transitions[(2*i+1) * KK + jj]; }
        else     { m0 = transitions[jj * KK + 2*i];
                   m1 = transitions[jj * KK + 2*i + 1]; }
        union { _Float16 h; unsigned short s; } h0, h1;
        h0.h = (_Float16)exp2f(m0 * L2E);
        h1.h = (_Float16)exp2f(m1 * L2E);
        Mp[i] = (unsigned)h0.s | ((unsigned)h1.s << 16);
    }
    // pin packed M in VGPRs (baseline's VGPR_Count=32 suggests it was not resident)
    #pragma unroll
    for (int i = 0; i < KK / 2; ++i) asm volatile("" : "+v"(Mp[i]));

    float u, Dbase;
    if (BWD) {
        u = ldexpf(exp2f(boundary[jj] * L2E), -ISC);   // f * 2^-SC
        Dbase = (float)ISC;
    } else {
        const float A0 = (boundary[jj] + em[jj]) * L2E;
        const float C0 = rlane(A0, 0);
        u = exp2f(A0 - C0 - (float)ISC);
        Dbase = C0 + (float)ISC;
    }
    int iD = 0, ip = 0;   // accumulated exponent, pending rescale
    const int tdir = BWD ? -1 : 1;

    auto STEP = [&](float E) {
        const float pv = BWD ? u * E : u;            // bwd folds E before M^T
        const unsigned upk = pack_pair(pv);
        unsigned x[KK / 2];
        #pragma unroll
        for (int i = 0; i < KK / 2; ++i)
            x[i] = (unsigned)__builtin_amdgcn_readlane((int)upk, 2 * i);
        float a0 = 0.f, a1 = 0.f, a2 = 0.f, a3 = 0.f;
        #pragma unroll
        for (int i = 0; i < KK / 2; i += 4) {
            a0 = dot2(x[i + 0], Mp[i + 0], a0);
            a1 = dot2(x[i + 1], Mp[i + 1], a1);
            a2 = dot2(x[i + 2], Mp[i + 2], a2);
            a3 = dot2(x[i + 3], Mp[i + 3], a3);
        }
        float ds = (a0 + a1) + (a2 + a3);
        if (!BWD) ds *= E;                            // fwd applies E after M
        u = ldexpf(ds, ip);                           // exact 2^ip rescale
        const float z = rlane(u, 0);                  // off-chain: feeds next step only
        const int e = (int)((__float_as_uint(z) >> 23) & 0xFFu) - 127;
        iD -= ip;
        ip = -ISC - e;
    };

    float curE[PF];
    #pragma unroll
    for (int k = 0; k < PF; ++k) {
        int t = t0 + tdir * k;
        t = t < 0 ? 0 : (t > TT - 1 ? TT - 1 : t);
        curE[k] = exp2f(em[(size_t)t * KK + jj] * L2E);
    }

    int s = 0;
    for (; s + PF <= nsteps; s += PF) {
        float nxt[PF];
        #pragma unroll
        for (int k = 0; k < PF; ++k) {
            int t = t0 + tdir * (s + PF + k);
            t = t < 0 ? 0 : (t > TT - 1 ? TT - 1 : t);
            nxt[k] = em[(size_t)t * KK + jj];
        }
        #pragma unroll
        for (int k = 0; k < PF; ++k) STEP(curE[k]);
        #pragma unroll
        for (int k = 0; k < PF; ++k) curE[k] = exp2f(nxt[k] * L2E);  // off-chain exp2
    }
    #pragma unroll
    for (int k = 0; k < PF; ++k)
        if (s + k < nsteps) STEP(curE[k]);

    u_out = u;
    D_out = Dbase + (float)iD;   // pending ip intentionally NOT applied
}

// One block per batch element, 3 waves:
//   wave 0: forward half  (steps 1..h),        h = L/2
//   wave 1: backward half (steps L-1..h+1)
//   wave 2: numerator path score
// Meet: log2(den) = Df + Db + log2(sum_j u_f[j] * g_b[j]);  out = score - ln2*log2(den)
__global__ __launch_bounds__(192, 1) void crf_all(
    const float* __restrict__ emissions,   // (B, T, K)
    const int*   __restrict__ tags,        // (B, T)
    const void*  __restrict__ mask,        // (B, T) — dtype probed
    const float* __restrict__ transitions, // (K, K)
    const float* __restrict__ start_t,     // (K,)
    const float* __restrict__ end_t,       // (K,)
    float*       __restrict__ out)         // (B,)
{
    const int b    = blockIdx.x;
    const int wave = threadIdx.x >> 6;
    const int lane = threadIdx.x & 63;
    __shared__ float sh_g[KK];
    __shared__ float sh_Db;
    __shared__ float sh_sc;

    const unsigned w0 = *((const unsigned*)mask);
    const int L = count_L(mask, b, lane, w0);
    const float* em = emissions + (size_t)b * TT * KK;
    const int h = L >> 1;

    float u_f = 0.0f, Df = 0.0f;
    if (wave == 0) {
        scan_half<0>(em, transitions, start_t, h, 1, lane, u_f, Df);
    } else if (wave == 1) {
        float g, Db;
        scan_half<1>(em, transitions, end_t, L - 1 - h, L - 1, lane, g, Db);
        if (lane < KK) sh_g[lane] = g;
        if (lane == 0) sh_Db = Db;
    } else {
        // numerator (verbatim from passing rounds)
        const int* tg = tags + (size_t)b * TT;
        float sc = 0.0f;
        for (int t = lane; t < TT; t += 64) {
            if (t < L) {
                const int tagt = tg[t];
                float term = em[(size_t)t * KK + tagt];
                term += (t == 0) ? start_t[tagt] : transitions[tg[t - 1] * KK + tagt];
                sc += term;
            }
        }
        sc = wave_reduce_sum_f(sc);
        if (lane == 0) sh_sc = sc + end_t[tg[L - 1]];
    }
    __syncthreads();
    if (wave == 0) {
        const float p  = (lane < KK) ? u_f * sh_g[lane] : 0.0f;
        const float ps = wave_reduce_sum_f(p);
        if (lane == 0) out[b] = sh_sc - LN2 * (Df + sh_Db + log2f(ps));
    }
}

extern "C" void kernel_launch(void* const* d_in, const int* in_sizes, int n_in,
                              void* d_out, int out_size, void* d_ws, size_t ws_size,
                              hipStream_t stream) {
    const float* emissions   = (const float*)d_in[0];
    const int*   tags        = (const int*)  d_in[1];
    const void*  mask        = (const void*) d_in[2];
    const float* transitions = (const float*)d_in[3];
    const float* start_t     = (const float*)d_in[4];
    const float* end_t       = (const float*)d_in[5];
    float* out = (float*)d_out;
    (void)d_ws; (void)ws_size;

    crf_all<<<BB, 192, 0, stream>>>(emissions, tags, mask, transitions,
                                    start_t, end_t, out);
}

// Round 2
// 256.092 us; speedup vs baseline: 1.1527x; 1.0273x over previous
//
#include <hip/hip_runtime.h>
#include <math.h>

#define BB 512
#define TT 1024
#define KK 48
#define PF 6      // emission prefetch depth (register ring)
#define ISC 12    // state kept at 2^-12 scale for f16 range
#define SEG 6     // segments per chain (min seg len = 511/6 = 85 >> rank-1 mixing depth ~10)
#define NW  (2*SEG - 1)   // 2*SEG-2 heavy waves + 1 numerator wave = 11 waves (704 thr)

typedef _Float16 half2v __attribute__((ext_vector_type(2)));

static constexpr float L2E = 1.4426950408889634f;   // log2(e)
static constexpr float LN2 = 0.6931471805599453f;   // ln(2)

__device__ __forceinline__ float wave_reduce_sum_f(float v) {
    #pragma unroll
    for (int m = 32; m >= 1; m >>= 1) v += __shfl_xor(v, m, 64);
    return v;
}
__device__ __forceinline__ int wave_reduce_sum_i(int v) {
    #pragma unroll
    for (int m = 32; m >= 1; m >>= 1) v += __shfl_xor(v, m, 64);
    return v;
}
__device__ __forceinline__ float rlane(float v, int i) {
    return __uint_as_float(__builtin_amdgcn_readlane(__float_as_uint(v), i));
}

// f16x2 dot product with f32 accumulate: v_dot2_f32_f16 (2 MACs / instr)
__device__ __forceinline__ float dot2(unsigned a, unsigned b, float c) {
#if __has_builtin(__builtin_amdgcn_fdot2)
    union { unsigned u; half2v h; } ua, ub;
    ua.u = a; ub.u = b;
    return __builtin_amdgcn_fdot2(ua.h, ub.h, c, false);
#else
    union { unsigned u; half2v h; } ua, ub;
    ua.u = a; ub.u = b;
    return c + (float)ua.h.x * (float)ub.h.x + (float)ua.h.y * (float)ub.h.y;
#endif
}

// Pack (u[j], u[j+1]) as f16x2 in-register: cvt -> DPP quad_perm swap -> byte-perm.
// Even lane j ends with (lo = u[j], hi = u[j+1]); readlanes target even lanes.
__device__ __forceinline__ unsigned pack_pair(float u) {
    union { _Float16 h; unsigned short s; } cv;
    cv.h = (_Float16)u;
    const unsigned own = cv.s;
    const unsigned nbr = (unsigned)__builtin_amdgcn_update_dpp(
        (int)own, (int)own, 0xB1 /*quad_perm [1,0,3,2]*/, 0xF, 0xF, false);
    return __builtin_amdgcn_perm(nbr, own, 0x05040100);
}

__device__ __forceinline__ int count_L(const void* mask, int b, int lane, unsigned w0) {
    int c = 0;
    if (w0 == 1u) {
        const int* mp = (const int*)mask + (size_t)b * TT;
        for (int t = lane; t < TT; t += 64) c += (mp[t] != 0);
    } else if (w0 == 0x3f800000u) {
        const float* mp = (const float*)mask + (size_t)b * TT;
        for (int t = lane; t < TT; t += 64) c += (mp[t] != 0.0f);
    } else {
        const unsigned char* mp = (const unsigned char*)mask + (size_t)b * TT;
        for (int t = lane; t < TT; t += 64) c += (mp[t] != 0);
    }
    return wave_reduce_sum_i(c);
}

// Scaled linear-space scan over nsteps emission steps of one segment.
// FWD (BWD=0): u <- E_t .* (M u),  t = t0 + s ascending.
// BWD (BWD=1): u <- M^T (E_t .* u), t = t0 - s descending.
// ONES=1: init u = ones (segment interior probe); else init from boundary vector.
// Renorm is an EXACT power-of-2 (exponent bits + ldexp), normalizer 1 step delayed
// (off the critical chain). True vector = u_out * 2^D_out.
template <int BWD, int ONES>
__device__ __forceinline__ void scan_seg(
    const float* __restrict__ em, const float* __restrict__ transitions,
    const float* __restrict__ boundary, int nsteps, int t0, int lane,
    float& u_out, float& D_out)
{
    const int jj = (lane < KK) ? lane : 0;
    unsigned Mp[KK / 2];   // fwd: row jj of exp(T); bwd: column jj of exp(T)
    #pragma unroll
    for (int i = 0; i < KK / 2; ++i) {
        float m0, m1;
        if (BWD) { m0 = transitions[(2*i)   * KK + jj];
                   m1 = transitions[(2*i+1) * KK + jj]; }
        else     { m0 = transitions[jj * KK + 2*i];
                   m1 = transitions[jj * KK + 2*i + 1]; }
        union { _Float16 h; unsigned short s; } h0, h1;
        h0.h = (_Float16)exp2f(m0 * L2E);
        h1.h = (_Float16)exp2f(m1 * L2E);
        Mp[i] = (unsigned)h0.s | ((unsigned)h1.s << 16);
    }
    #pragma unroll
    for (int i = 0; i < KK / 2; ++i) asm volatile("" : "+v"(Mp[i]));

    float u, Dbase;
    if (ONES) {
        u = ldexpf(1.0f, -ISC);
        Dbase = (float)ISC;
    } else if (BWD) {
        u = ldexpf(exp2f(boundary[jj] * L2E), -ISC);   // f = exp(end), scaled
        Dbase = (float)ISC;
    } else {
        const float A0 = (boundary[jj] + em[jj]) * L2E; // u0 from start + em[t=0]
        const float C0 = rlane(A0, 0);
        u = exp2f(A0 - C0 - (float)ISC);
        Dbase = C0 + (float)ISC;
    }
    int iD = 0, ip = 0;   // accumulated exponent, pending rescale
    const int tdir = BWD ? -1 : 1;

    auto STEP = [&](float E) {
        const float pv = BWD ? u * E : u;            // bwd folds E before M^T
        const unsigned upk = pack_pair(pv);
        unsigned x[KK / 2];
        #pragma unroll
        for (int i = 0; i < KK / 2; ++i)
            x[i] = (unsigned)__builtin_amdgcn_readlane((int)upk, 2 * i);
        float a0 = 0.f, a1 = 0.f, a2 = 0.f, a3 = 0.f;
        #pragma unroll
        for (int i = 0; i < KK / 2; i += 4) {
            a0 = dot2(x[i + 0], Mp[i + 0], a0);
            a1 = dot2(x[i + 1], Mp[i + 1], a1);
            a2 = dot2(x[i + 2], Mp[i + 2], a2);
            a3 = dot2(x[i + 3], Mp[i + 3], a3);
        }
        float ds = (a0 + a1) + (a2 + a3);
        if (!BWD) ds *= E;                            // fwd applies E after M
        u = ldexpf(ds, ip);                           // exact 2^ip rescale
        const float z = rlane(u, 0);                  // off-chain: feeds next step only
        const int e = (int)((__float_as_uint(z) >> 23) & 0xFFu) - 127;
        iD -= ip;
        ip = -ISC - e;
    };

    float curE[PF];
    #pragma unroll
    for (int k = 0; k < PF; ++k) {
        int t = t0 + tdir * k;
        t = t < 0 ? 0 : (t > TT - 1 ? TT - 1 : t);
        curE[k] = exp2f(em[(size_t)t * KK + jj] * L2E);
    }

    int s = 0;
    for (; s + PF <= nsteps; s += PF) {
        float nxt[PF];
        #pragma unroll
        for (int k = 0; k < PF; ++k) {
            int t = t0 + tdir * (s + PF + k);
            t = t < 0 ? 0 : (t > TT - 1 ? TT - 1 : t);
            nxt[k] = em[(size_t)t * KK + jj];
        }
        #pragma unroll
        for (int k = 0; k < PF; ++k) STEP(curE[k]);
        #pragma unroll
        for (int k = 0; k < PF; ++k) curE[k] = exp2f(nxt[k] * L2E);  // off-chain exp2
    }
    #pragma unroll
    for (int k = 0; k < PF; ++k)
        if (s + k < nsteps) STEP(curE[k]);

    u_out = u;
    D_out = Dbase + (float)iD;
}

// One block per batch element, NW = 11 waves:
//   waves 0..SEG-2   : fwd scans. wave 0: x = B0 u0 (true start); wave i: p_i = B_i 1
//   waves SEG-1..2SEG-3: bwd scans. seg i = wid-SEG+2: m_i = B_i^T 1; last: y = B_{S-1}^T f
//   wave 2SEG-2      : numerator path score
// Splice (inner products of long positive-matrix segments are rank-1 to f32):
//   den = (m1.x) * prod_i (m_{i+1}.p_i) * (y.p_{S-2}) / prod_i (1.p_i)
__global__ __launch_bounds__(64 * NW, 6) void crf_all(
    const float* __restrict__ emissions,   // (B, T, K)
    const int*   __restrict__ tags,        // (B, T)
    const void*  __restrict__ mask,        // (B, T) — dtype probed
    const float* __restrict__ transitions, // (K, K)
    const float* __restrict__ start_t,     // (K,)
    const float* __restrict__ end_t,       // (K,)
    float*       __restrict__ out)         // (B,)
{
    const int b    = blockIdx.x;
    const int wid  = threadIdx.x >> 6;
    const int lane = threadIdx.x & 63;
    __shared__ float sh_vec[2 * SEG - 2][KK];   // slots: 0..S-2 = x,p1..p_{S-2}; S-1..2S-3 = m1..m_{S-2},y
    __shared__ float sh_D[2 * SEG - 2];
    __shared__ float sh_sc;

    const unsigned w0 = *((const unsigned*)mask);
    const int L = count_L(mask, b, lane, w0);
    const float* em = emissions + (size_t)b * TT * KK;

    const int N    = L - 1;          // steps t = 1..L-1
    const int base = N / SEG;
    const int rem  = N % SEG;

    if (wid < 2 * SEG - 2) {
        const int i   = (wid < SEG - 1) ? wid : (wid - SEG + 2);  // segment index
        const int len = base + (i < rem ? 1 : 0);
        const int a   = 1 + i * base + (i < rem ? i : rem);       // first step t of segment
        float u, D;
        if (wid < SEG - 1) {
            if (i == 0) scan_seg<0, 0>(em, transitions, start_t, len, a, lane, u, D);
            else        scan_seg<0, 1>(em, transitions, nullptr, len, a, lane, u, D);
            if (lane < KK) sh_vec[i][lane] = u;
            if (lane == 0) sh_D[i] = D;
        } else {
            const int t0 = a + len - 1;
            if (i == SEG - 1) scan_seg<1, 0>(em, transitions, end_t, len, t0, lane, u, D);
            else              scan_seg<1, 1>(em, transitions, nullptr, len, t0, lane, u, D);
            const int slot = SEG - 2 + i;   // m_i at S-2+i (i=1..S-2), y at 2S-3
            if (lane < KK) sh_vec[slot][lane] = u;
            if (lane == 0) sh_D[slot] = D;
        }
    } else {
        // numerator (verbatim from passing rounds)
        const int* tg = tags + (size_t)b * TT;
        float sc = 0.0f;
        for (int t = lane; t < TT; t += 64) {
            if (t < L) {
                const int tagt = tg[t];
                float term = em[(size_t)t * KK + tagt];
                term += (t == 0) ? start_t[tagt] : transitions[tg[t - 1] * KK + tagt];
                sc += term;
            }
        }
        sc = wave_reduce_sum_f(sc);
        if (lane == 0) sh_sc = sc + end_t[tg[L - 1]];
    }
    __syncthreads();

    if (wid == 0) {
        float acc = 0.0f;
        // product terms: (G slot S-1+k) . (F slot k), k = 0..S-2
        #pragma unroll
        for (int k = 0; k < SEG - 1; ++k) {
            const float pr = (lane < KK) ? sh_vec[SEG - 1 + k][lane] * sh_vec[k][lane] : 0.0f;
            const float s  = wave_reduce_sum_f(pr);
            acc += log2f(s) + sh_D[SEG - 1 + k] + sh_D[k];
        }
        // normalizers: 1 . p_i, i = 1..S-2
        #pragma unroll
        for (int i = 1; i <= SEG - 2; ++i) {
            const float v = (lane < KK) ? sh_vec[i][lane] : 0.0f;
            const float s = wave_reduce_sum_f(v);
            acc -= log2f(s) + sh_D[i];
        }
        if (lane == 0) out[b] = sh_sc - LN2 * acc;
    }
}

extern "C" void kernel_launch(void* const* d_in, const int* in_sizes, int n_in,
                              void* d_out, int out_size, void* d_ws, size_t ws_size,
                              hipStream_t stream) {
    const float* emissions   = (const float*)d_in[0];
    const int*   tags        = (const int*)  d_in[1];
    const void*  mask        = (const void*) d_in[2];
    const float* transitions = (const float*)d_in[3];
    const float* start_t     = (const float*)d_in[4];
    const float* end_t       = (const float*)d_in[5];
    float* out = (float*)d_out;
    (void)d_ws; (void)ws_size;

    crf_all<<<BB, 64 * NW, 0, stream>>>(emissions, tags, mask, transitions,
                                        start_t, end_t, out);
}

// Round 5
// 178.819 us; speedup vs baseline: 1.6508x; 1.4321x over previous
//
#include <hip/hip_runtime.h>
#include <math.h>

#define BB 512
#define TT 1024
#define KK 48
#define SEG 17       // segments per chain; fwd scans = bwd scans = 16 = MFMA columns
#define CENTER 6     // keep |B| centered near 2^-CENTER for f16 headroom

typedef _Float16 f16x8 __attribute__((ext_vector_type(8)));
typedef float    f32x4 __attribute__((ext_vector_type(4)));

static constexpr float L2E = 1.4426950408889634f;   // log2(e)
static constexpr float LN2 = 0.6931471805599453f;   // ln(2)

__device__ __forceinline__ float wave_reduce_sum_f(float v) {
    #pragma unroll
    for (int m = 32; m >= 1; m >>= 1) v += __shfl_xor(v, m, 64);
    return v;
}
__device__ __forceinline__ int wave_reduce_sum_i(int v) {
    #pragma unroll
    for (int m = 32; m >= 1; m >>= 1) v += __shfl_xor(v, m, 64);
    return v;
}

__device__ __forceinline__ int count_L(const void* mask, int b, int lane, unsigned w0) {
    int c = 0;
    if (w0 == 1u) {
        const int* mp = (const int*)mask + (size_t)b * TT;
        for (int t = lane; t < TT; t += 64) c += (mp[t] != 0);
    } else if (w0 == 0x3f800000u) {
        const float* mp = (const float*)mask + (size_t)b * TT;
        for (int t = lane; t < TT; t += 64) c += (mp[t] != 0.0f);
    } else {
        const unsigned char* mp = (const unsigned char*)mask + (size_t)b * TT;
        for (int t = lane; t < TT; t += 64) c += (mp[t] != 0);
    }
    return wave_reduce_sum_i(c);
}

__device__ __forceinline__ f32x4 mfma16(f16x8 a, f16x8 b, f32x4 c) {
    return __builtin_amdgcn_mfma_f32_16x16x32_f16(a, b, c, 0, 0, 0);
}

// max over the 12 per-lane state elements (values are positive; 0 floor harmless)
__device__ __forceinline__ float max12(const f32x4* v) {
    float mx = 0.0f;
    #pragma unroll
    for (int m = 0; m < 3; ++m) {
        #pragma unroll
        for (int e = 0; e < 4; ++e) mx = fmaxf(mx, v[m][e]);
    }
    return mx;
}

// Pack state rows into B fragments (in-lane: C/D row 16m+4g+e == B k-slot mapping).
// B0 = ks {4g..4g+3} U {16+4g..16+4g+3}; B1 = ks {32+4g..32+4g+3} U zero-pad (k>=48).
__device__ __forceinline__ void pack_b(const f32x4* braw, f16x8& B0, f16x8& B1) {
    B0 = (f16x8){(_Float16)braw[0][0], (_Float16)braw[0][1],
                 (_Float16)braw[0][2], (_Float16)braw[0][3],
                 (_Float16)braw[1][0], (_Float16)braw[1][1],
                 (_Float16)braw[1][2], (_Float16)braw[1][3]};
    B1 = (f16x8){(_Float16)braw[2][0], (_Float16)braw[2][1],
                 (_Float16)braw[2][2], (_Float16)braw[2][3],
                 (_Float16)0, (_Float16)0, (_Float16)0, (_Float16)0};
}

// 16 segment-scans of one chain as 16 MFMA columns.
// FWD=0: column c = fwd segment i=c:  u <- E_t .* (M u), t ascending from a.
//        c==0 init exp(start+em[0]); else ones.
// BWD=1: column c = bwd segment i=c+1: u <- M^T (E_t .* u), t descending from t0.
//        c==15 init exp(end); else ones.
// State per step: B(f16) = U * 2^-D (exact power-of-2 ledger, delayed renorm).
// Output: sh_V[c][j] (f32) and sh_D[c]; true vector = V * 2^D.
template <int BWD>
__device__ void scan_mfma(
    const float* __restrict__ em, const float* __restrict__ transitions,
    const float* __restrict__ start_t, const float* __restrict__ end_t,
    int Lb, int lane, float (*sh_V)[KK], float* sh_D)
{
    const int c = lane & 15;
    const int g = lane >> 4;
    const int i = BWD ? (c + 1) : c;
    const int N = Lb - 1;
    const int base = N / SEG, rem = N % SEG;
    const int len  = base + ((i < rem) ? 1 : 0);
    const int a    = 1 + i * base + ((i < rem) ? i : rem);
    const bool extra = (len > base);                       // per-lane
    const int nsteps = base + ((BWD ? (rem >= 2) : (rem >= 1)) ? 1 : 0);

    // ---- A fragments: 3 row-tiles x 2 K-chunks (K padded 48->64 with zeros)
    // element e of chunk ch: k = 32*ch + 16*(e>>2) + 4*g + (e&3); row j = 16*r + c
    f16x8 A[3][2];
    #pragma unroll
    for (int r = 0; r < 3; ++r) {
        #pragma unroll
        for (int ch = 0; ch < 2; ++ch) {
            f16x8 fr;
            #pragma unroll
            for (int e = 0; e < 8; ++e) {
                const int k = 32 * ch + 16 * (e >> 2) + 4 * g + (e & 3);
                const int j = 16 * r + c;
                float tv = 0.0f;
                if (k < KK)
                    tv = exp2f((BWD ? transitions[k * KK + j]
                                    : transitions[j * KK + k]) * L2E);
                fr[e] = (_Float16)tv;
            }
            A[r][ch] = fr;
        }
    }

    const int t0 = a + len - 1;
    const float* pe = em + (size_t)(BWD ? t0 : a) * KK + 4 * g;  // +16*m per chunk
    const int pstep = BWD ? -KK : KK;

    // ---- init state Braw (rows k = 16*m + 4g + e, col c)
    f32x4 braw[3];
    #pragma unroll
    for (int m = 0; m < 3; ++m) {
        f32x4 bv;
        #pragma unroll
        for (int e = 0; e < 4; ++e) {
            const int k = 16 * m + 4 * g + e;
            float u0;
            if (BWD) u0 = (c == 15) ? exp2f(end_t[k] * L2E) : 1.0f;
            else     u0 = (c == 0) ? exp2f((start_t[k] + em[k]) * L2E) : 1.0f;
            bv[e] = u0;
        }
        braw[m] = bv;
    }
    if (BWD) {   // bwd folds E at t0 into the init state
        #pragma unroll
        for (int m = 0; m < 3; ++m) {
            const f32x4 ev = *(const f32x4*)(pe + 16 * m);
            #pragma unroll
            for (int e = 0; e < 4; ++e) braw[m][e] *= exp2f(ev[e] * L2E);
        }
        pe += pstep;                       // now at tE(1) = t0-1
    }

    // emission for step 1 (fwd: t=a; bwd: t=t0-1)
    f32x4 cur[3], nxt[3];
    #pragma unroll
    for (int m = 0; m < 3; ++m) cur[m] = *(const f32x4*)(pe + 16 * m);
    pe += pstep;

    int D = 0;
    float mx = max12(braw);
    mx = fmaxf(mx, __shfl_xor(mx, 16));
    mx = fmaxf(mx, __shfl_xor(mx, 32));
    int dadj = (int)((__float_as_uint(mx) >> 23) & 0xFF) - 127 + CENTER;

    f16x8 B0, B1;
    pack_b(braw, B0, B1);

    f32x4 C[3], snapV[3];
    int snapD = 0;
    #pragma unroll
    for (int m = 0; m < 3; ++m) snapV[m] = braw[m];

    #pragma unroll 1
    for (int s = 1; s <= nsteps; ++s) {
        // prefetch emission for step s+1 (may overrun by 1 step; stays in-array)
        #pragma unroll
        for (int m = 0; m < 3; ++m) nxt[m] = *(const f32x4*)(pe + 16 * m);
        pe += pstep;

        // C = M (fwd) / M^T (bwd) times B
        #pragma unroll
        for (int r = 0; r < 3; ++r) {
            f32x4 z = {0.0f, 0.0f, 0.0f, 0.0f};
            z = mfma16(A[r][0], B0, z);
            z = mfma16(A[r][1], B1, z);
            C[r] = z;
        }

        if (BWD && s == base) {            // bwd output = C, D pre-update
            #pragma unroll
            for (int m = 0; m < 3; ++m) snapV[m] = C[m];
            snapD = D;
        }

        if (!BWD || s <= base) {           // bwd skips conversion on its extra step
            const float nd = -(float)dadj;
            #pragma unroll
            for (int m = 0; m < 3; ++m) {
                #pragma unroll
                for (int e = 0; e < 4; ++e)
                    braw[m][e] = C[m][e] * exp2f(fmaf(cur[m][e], L2E, nd));
            }
            D += dadj;
            float mx2 = max12(braw);
            mx2 = fmaxf(mx2, __shfl_xor(mx2, 16));
            mx2 = fmaxf(mx2, __shfl_xor(mx2, 32));
            dadj = (int)((__float_as_uint(mx2) >> 23) & 0xFF) - 127 + CENTER;
            pack_b(braw, B0, B1);
            if (!BWD && s == base) {       // fwd output = Braw, D post-update
                #pragma unroll
                for (int m = 0; m < 3; ++m) snapV[m] = braw[m];
                snapD = D;
            }
        }
        #pragma unroll
        for (int m = 0; m < 3; ++m) cur[m] = nxt[m];
    }

    // per-column select: columns with len = base+1 take the final state
    f32x4 V[3];
    int Dout;
    if (BWD) {
        #pragma unroll
        for (int m = 0; m < 3; ++m) {
            #pragma unroll
            for (int e = 0; e < 4; ++e) V[m][e] = extra ? C[m][e] : snapV[m][e];
        }
        Dout = extra ? D : snapD;
    } else {
        #pragma unroll
        for (int m = 0; m < 3; ++m) {
            #pragma unroll
            for (int e = 0; e < 4; ++e) V[m][e] = extra ? braw[m][e] : snapV[m][e];
        }
        Dout = extra ? D : snapD;
    }

    #pragma unroll
    for (int r = 0; r < 3; ++r) {
        #pragma unroll
        for (int e = 0; e < 4; ++e)
            sh_V[c][16 * r + 4 * g + e] = V[r][e];
    }
    if (g == 0) sh_D[c] = (float)Dout;
}

// One block per batch element, 3 waves: fwd-scan wave, bwd-scan wave, numerator wave.
// Splice: den = (m1.x) * prod_i (m_{i+1}.p_i) * (y.p_{S-2}) / prod_i (1.p_i)
__global__ __launch_bounds__(192, 1) void crf_all(
    const float* __restrict__ emissions,   // (B, T, K)
    const int*   __restrict__ tags,        // (B, T)
    const void*  __restrict__ mask,        // (B, T) — dtype probed
    const float* __restrict__ transitions, // (K, K)
    const float* __restrict__ start_t,     // (K,)
    const float* __restrict__ end_t,       // (K,)
    float*       __restrict__ out)         // (B,)
{
    const int b    = blockIdx.x;
    const int wid  = threadIdx.x >> 6;
    const int lane = threadIdx.x & 63;
    __shared__ float sh_F[16][KK];
    __shared__ float sh_G[16][KK];
    __shared__ float sh_DF[16];
    __shared__ float sh_DG[16];
    __shared__ float sh_sc;

    const unsigned w0 = *((const unsigned*)mask);
    const int L = count_L(mask, b, lane, w0);
    const float* em = emissions + (size_t)b * TT * KK;

    if (wid == 0) {
        scan_mfma<0>(em, transitions, start_t, end_t, L, lane, sh_F, sh_DF);
    } else if (wid == 1) {
        scan_mfma<1>(em, transitions, start_t, end_t, L, lane, sh_G, sh_DG);
    } else {
        // numerator (verbatim from passing rounds)
        const int* tg = tags + (size_t)b * TT;
        float sc = 0.0f;
        for (int t = lane; t < TT; t += 64) {
            if (t < L) {
                const int tagt = tg[t];
                float term = em[(size_t)t * KK + tagt];
                term += (t == 0) ? start_t[tagt] : transitions[tg[t - 1] * KK + tagt];
                sc += term;
            }
        }
        sc = wave_reduce_sum_f(sc);
        if (lane == 0) sh_sc = sc + end_t[tg[L - 1]];
    }
    __syncthreads();

    if (wid == 0) {
        // acc = sum_k [log2(G_k.F_k) + DG_k] - sum_{k>=1} log2(1.F_k)  (DF_k cancels, k>=1)
        const int k = lane >> 2;
        const int q = lane & 3;
        float dot = 0.0f, ns = 0.0f;
        #pragma unroll
        for (int e = 0; e < 12; ++e) {
            const int j = q * 12 + e;
            const float f = sh_F[k][j];
            dot += sh_G[k][j] * f;
            ns  += f;
        }
        dot += __shfl_xor(dot, 1, 64); dot += __shfl_xor(dot, 2, 64);
        ns  += __shfl_xor(ns, 1, 64);  ns  += __shfl_xor(ns, 2, 64);
        float v = 0.0f;
        if (q == 0) {
            v = log2f(dot) + sh_DG[k];
            if (k >= 1) v -= log2f(ns);
        }
        const float acc = wave_reduce_sum_f(v);
        if (lane == 0) out[b] = sh_sc - LN2 * (acc + sh_DF[0]);
    }
}

extern "C" void kernel_launch(void* const* d_in, const int* in_sizes, int n_in,
                              void* d_out, int out_size, void* d_ws, size_t ws_size,
                              hipStream_t stream) {
    const float* emissions   = (const float*)d_in[0];
    const int*   tags        = (const int*)  d_in[1];
    const void*  mask        = (const void*) d_in[2];
    const float* transitions = (const float*)d_in[3];
    const float* start_t     = (const float*)d_in[4];
    const float* end_t       = (const float*)d_in[5];
    float* out = (float*)d_out;
    (void)d_ws; (void)ws_size;

    crf_all<<<BB, 192, 0, stream>>>(emissions, tags, mask, transitions,
                                    start_t, end_t, out);
}